// Round 16
// baseline (85.953 us; speedup 1.0000x reference)
//
#include <hip/hip_runtime.h>

typedef float f32x4 __attribute__((ext_vector_type(4)));
typedef short s16x8 __attribute__((ext_vector_type(8)));

#define CB_PLANE 2704   // 52*52 ushorts
#define CB_ROW 52

// d_ws layout (ushort units) — R11 proven
#define WS_H2G  0                 // 4096*288
#define WS_FW1  1179648           // 256*288
#define WS_W1   1253376           // 16*192
#define WS_W2   1256448           // 32*256

// software f32->bf16 RNE (proven R3-R15)
__device__ __forceinline__ ushort f2bf(float f) {
  unsigned u = __float_as_uint(f);
  unsigned r = (u + 0x7fffu + ((u >> 16) & 1u)) >> 16;
  return (ushort)r;
}
__device__ __forceinline__ uint pk2(float a, float b) {
  return (uint)f2bf(a) | ((uint)f2bf(b) << 16);
}

// ---- prep: convert fw1 (73728), w1 (3072), w2 (8192) to bf16. 332*256 exact
__global__ void prep_kernel(const float* __restrict__ fw1,
                            const float* __restrict__ w1,
                            const float* __restrict__ w2,
                            ushort* __restrict__ ws) {
  int i = blockIdx.x * 256 + threadIdx.x;
  if (i < 73728)       ws[WS_FW1 + i] = f2bf(fw1[i]);
  else if (i < 76800)  ws[WS_W1 + i - 73728] = f2bf(w1[i - 73728]);
  else                 ws[WS_W2 + i - 76800] = f2bf(w2[i - 76800]);
}

// ---- conv1 epilogue: bias+relu, scatter into conv2 im2col (proven R8) ----
__device__ __forceinline__ void epi1(ushort* A2, f32x4 acc, int mt, int r16,
                                     int g, float b1v) {
#pragma unroll
  for (int rr = 0; rr < 4; ++rr) {
    int m = mt * 16 + g * 4 + rr;
    int oy = m / 12, ox = m - 12 * oy;
    if (oy < 11 && ox < 11) {
      float v = fmaxf(acc[rr] + b1v, 0.f);
      int py = (oy + 1) >> 2, k2y = (oy + 1) & 3;
      int px = (ox + 1) >> 2, k2x = (ox + 1) & 3;
      A2[(py * 3 + px) * 264 + r16 * 16 + k2y * 4 + k2x] = f2bf(v);   // rows 0..8 only
    }
  }
}

// == Kernel A: conv1+conv2, 2 cells/block, lean LDS (20976 B -> 7 blocks/CU) ==
// A2 holds only its 9 live rows; conv2's A-fragment reads for r16 in 9..15
// overflow into cb (deterministic garbage) and feed only discarded C rows
// (MFMA: A row m affects only C row m). A2 placed FIRST in one smem array so
// the overflow stays inside this block's LDS allocation.
__global__ __launch_bounds__(256, 7)
void conv_kernel(const float* __restrict__ x,
                 const ushort* __restrict__ w1b, const float* __restrict__ b1,
                 const ushort* __restrict__ w2b, const float* __restrict__ b2,
                 ushort* __restrict__ h2g)
{
  __shared__ __align__(16) ushort smem[9 * 264 + 3 * CB_PLANE];  // 20976 B
  ushort* A2 = smem;              // 2376 ushorts
  ushort* cb = smem + 9 * 264;    // 8112 ushorts, byte base 4752 (16-aligned)

  const int t = threadIdx.x;
  const int w = t >> 6;
  const int r16 = t & 15;
  const int g = (t & 63) >> 4;
  const int cell0 = blockIdx.x * 2;

  // ---- staging descriptors (cell-invariant): 1728 float4 over 7 slots ----
  int goff[7], eoff[7];
#pragma unroll
  for (int i = 0; i < 7; ++i) {
    int q = i * 256 + t;
    int qq = (i < 6 || t < 192) ? q : 0;
    int c = qq / 576; int r2 = qq - c * 576;
    int y = r2 / 12;  int quad = r2 - y * 12;
    goff[i] = c * 36864 + y * 96 + quad;
    eoff[i] = c * CB_PLANE + (y + 2) * CB_ROW + 2 + quad * 4;
  }
  const float4* x4 = (const float4*)x;

  // ---- issue cell0 loads immediately (raw float4) ----
  float4 v[7];
  {
    int n = cell0, b = n >> 6, gg = n & 63;
    int base4 = b * 110592 + (gg >> 3) * 4608 + (gg & 7) * 12;
#pragma unroll
    for (int i = 0; i < 7; ++i)
      if (i < 6 || t < 192) v[i] = x4[base4 + goff[i]];
  }

  // ---- zero cb borders (persist; disjoint from interior writes) + A2 ----
  for (int i = t; i < 600; i += 256) {
    int pl = i / 200, r = i - pl * 200;
    int off;
    if (r < 52)        off = r;
    else if (r < 104)  off = 1300 + (r - 52);
    else if (r < 152)  off = (2 + (r - 104)) * 26;
    else               off = (2 + (r - 152)) * 26 + 25;
    ((uint*)cb)[pl * 1352 + off] = 0u;
  }
  for (int i = t; i < 1188; i += 256) ((uint*)A2)[i] = 0u;   // 9*264/2

  // ---- conv1 B-fragments from pre-converted w1b ----
  s16x8 b1f[6];
#pragma unroll
  for (int s = 0; s < 6; ++s)
    b1f[s] = *(const s16x8*)&w1b[r16 * 192 + s * 32 + g * 8];
  const float b1v = b1[r16];
  const float b2v = b2[(w & 1) * 16 + r16];

  // ---- write cell0 to cb (convert here, once per pixel) ----
#pragma unroll
  for (int i = 0; i < 7; ++i)
    if (i < 6 || t < 192) {
      uint* d = (uint*)&cb[eoff[i]];
      d[0] = pk2(v[i].x, v[i].y);
      d[1] = pk2(v[i].z, v[i].w);
    }

  // conv1 lane constants: wave w owns m-tiles {w, w+4}, wave 2 also 8
  const int mt0 = w, mt1 = w + 4;
  int m0 = mt0 * 16 + r16, m1 = mt1 * 16 + r16, m2_ = 128 + r16;
  const int rA0 = (m0 / 12) * (4 * CB_ROW) + 4 * (m0 % 12);
  const int rA1 = (m1 / 12) * (4 * CB_ROW) + 4 * (m1 % 12);
  const int rA2 = (m2_ / 12) * (4 * CB_ROW) + 4 * (m2_ % 12);

  __syncthreads();

  for (int cl = 0; cl < 2; ++cl) {
    // ---- issue next cell's loads (raw; first USE is after mid-bar) ----
    if (cl < 1) {
      int n = cell0 + 1, b = n >> 6, gg = n & 63;
      int base4 = b * 110592 + (gg >> 3) * 4608 + (gg & 7) * 12;
#pragma unroll
      for (int i = 0; i < 7; ++i)
        if (i < 6 || t < 192) v[i] = x4[base4 + goff[i]];
    }

    // ---- conv1 MFMA on cb (cell cl) ----
    f32x4 a0 = (f32x4){0.f, 0.f, 0.f, 0.f};
    f32x4 a1 = (f32x4){0.f, 0.f, 0.f, 0.f};
    f32x4 a2 = (f32x4){0.f, 0.f, 0.f, 0.f};
#pragma unroll
    for (int s = 0; s < 6; ++s) {
      int sbase = (s >> 1) * CB_PLANE + ((s & 1) * 4 + g) * CB_ROW;
      s16x8 a;
      ((uint2*)&a)[0] = *(const uint2*)&cb[sbase + rA0];
      ((uint2*)&a)[1] = *(const uint2*)&cb[sbase + rA0 + 4];
      a0 = __builtin_amdgcn_mfma_f32_16x16x32_bf16(a, b1f[s], a0, 0, 0, 0);
      ((uint2*)&a)[0] = *(const uint2*)&cb[sbase + rA1];
      ((uint2*)&a)[1] = *(const uint2*)&cb[sbase + rA1 + 4];
      a1 = __builtin_amdgcn_mfma_f32_16x16x32_bf16(a, b1f[s], a1, 0, 0, 0);
      if (w == 2) {
        ((uint2*)&a)[0] = *(const uint2*)&cb[sbase + rA2];
        ((uint2*)&a)[1] = *(const uint2*)&cb[sbase + rA2 + 4];
        a2 = __builtin_amdgcn_mfma_f32_16x16x32_bf16(a, b1f[s], a2, 0, 0, 0);
      }
    }
    epi1(A2, a0, mt0, r16, g, b1v);
    epi1(A2, a1, mt1, r16, g, b1v);
    if (w == 2) epi1(A2, a2, 8, r16, g, b1v);

    __syncthreads();   // conv1 reads of cb done; A2 complete

    // ---- conv2 (waves 0,1) + staging write of cell cl+1 (all waves) ----
    if (w < 2) {
      f32x4 c2acc = (f32x4){0.f, 0.f, 0.f, 0.f};
#pragma unroll
      for (int s2 = 0; s2 < 8; ++s2) {
        uint4 av = *(const uint4*)&A2[r16 * 264 + s2 * 32 + g * 8];  // r16>=9: garbage, discarded
        s16x8 bf = *(const s16x8*)&w2b[(w * 16 + r16) * 256 + s2 * 32 + g * 8];
        c2acc = __builtin_amdgcn_mfma_f32_16x16x32_bf16(*(s16x8*)&av, bf, c2acc, 0, 0, 0);
      }
#pragma unroll
      for (int rr = 0; rr < 4; ++rr) {
        int p2 = g * 4 + rr;
        if (p2 < 9) {
          float vv = fmaxf(c2acc[rr] + b2v, 0.f);
          h2g[(cell0 + cl) * 288 + (w * 16 + r16) * 9 + p2] = f2bf(vv);
        }
      }
    }
    if (cl < 1) {
#pragma unroll
      for (int i = 0; i < 7; ++i)
        if (i < 6 || t < 192) {
          uint* d = (uint*)&cb[eoff[i]];
          d[0] = pk2(v[i].x, v[i].y);
          d[1] = pk2(v[i].z, v[i].w);
        }
    }
    __syncthreads();   // staging writes + conv2 A2 reads complete
  }
}

// ============ Kernel B: fc1(MFMA) + fc2 + softmax (unchanged R11) ==========
__global__ __launch_bounds__(256, 4)
void fc_kernel(const ushort* __restrict__ fw1b, const float* __restrict__ fb1,
               const float* __restrict__ fw2, const float* __restrict__ fb2,
               const ushort* __restrict__ h2g, float* __restrict__ out)
{
  __shared__ __align__(16) ushort h2s[16 * 296];
  __shared__ __align__(16) float h3s[16 * 260];
  __shared__ float ls[16][4];

  const int t = threadIdx.x;
  const int w = t >> 6;
  const int r16 = t & 15;
  const int g = (t & 63) >> 4;
  const int c0 = blockIdx.x * 16;

  const uint* src = (const uint*)(h2g + c0 * 288);
  for (int j = t; j < 2304; j += 256) {
    int r = j / 144, ci = j - r * 144;
    *(uint*)&h2s[r * 296 + 2 * ci] = src[j];
  }
  __syncthreads();

  s16x8 af[9];
#pragma unroll
  for (int s = 0; s < 9; ++s)
    af[s] = *(const s16x8*)&h2s[r16 * 296 + s * 32 + g * 8];

  f32x4 fa0 = (f32x4){0.f,0.f,0.f,0.f}, fa1 = fa0, fa2 = fa0, fa3 = fa0;
#pragma unroll
  for (int s = 0; s < 9; ++s) {
    const int ko = s * 32 + g * 8;
#pragma unroll
    for (int i = 0; i < 4; ++i) {
      s16x8 bf = *(const s16x8*)&fw1b[((w * 4 + i) * 16 + r16) * 288 + ko];
      if (i == 0) fa0 = __builtin_amdgcn_mfma_f32_16x16x32_bf16(af[s], bf, fa0, 0, 0, 0);
      if (i == 1) fa1 = __builtin_amdgcn_mfma_f32_16x16x32_bf16(af[s], bf, fa1, 0, 0, 0);
      if (i == 2) fa2 = __builtin_amdgcn_mfma_f32_16x16x32_bf16(af[s], bf, fa2, 0, 0, 0);
      if (i == 3) fa3 = __builtin_amdgcn_mfma_f32_16x16x32_bf16(af[s], bf, fa3, 0, 0, 0);
    }
  }
#pragma unroll
  for (int i = 0; i < 4; ++i) {
    f32x4 fa = (i == 0) ? fa0 : (i == 1) ? fa1 : (i == 2) ? fa2 : fa3;
    int n = (w * 4 + i) * 16 + r16;
    float fb = fb1[n];
#pragma unroll
    for (int rr = 0; rr < 4; ++rr)
      h3s[(g * 4 + rr) * 260 + n] = fmaxf(fa[rr] + fb, 0.f);
  }
  __syncthreads();

  {
    int u = t >> 2, sub = t & 3;
    int cl = u >> 2, j = u & 3;
    const float4* hp = (const float4*)&h3s[cl * 260];
    const float4* wp = (const float4*)(fw2 + j * 256);
    float p = 0.f;
#pragma unroll
    for (int i = 0; i < 16; ++i) {
      int k4 = sub + 4 * i;
      float4 a = hp[k4], bb = wp[k4];
      p = fmaf(a.x, bb.x, p); p = fmaf(a.y, bb.y, p);
      p = fmaf(a.z, bb.z, p); p = fmaf(a.w, bb.w, p);
    }
    p += __shfl_xor(p, 1);
    p += __shfl_xor(p, 2);
    if (sub == 0) ls[cl][j] = p + fb2[j];
  }
  __syncthreads();

  if (t < 16) {
    float l0 = ls[t][0], l1 = ls[t][1], l2 = ls[t][2], l3 = ls[t][3];
    float m = fmaxf(fmaxf(l0, l1), fmaxf(l2, l3));
    float e0 = __expf(l0 - m), e1 = __expf(l1 - m),
          e2 = __expf(l2 - m), e3 = __expf(l3 - m);
    float inv = 1.f / (e0 + e1 + e2 + e3);
    int n = c0 + t;
    out[n] = e0 * inv;
    out[4096 + n] = e1 * inv;
    out[8192 + n] = e2 * inv;
  }
}

extern "C" void kernel_launch(void* const* d_in, const int* in_sizes, int n_in,
                              void* d_out, int out_size, void* d_ws, size_t ws_size,
                              hipStream_t stream) {
  const float* x   = (const float*)d_in[0];
  const float* w1  = (const float*)d_in[1];
  const float* b1  = (const float*)d_in[2];
  const float* w2  = (const float*)d_in[3];
  const float* b2  = (const float*)d_in[4];
  const float* fw1 = (const float*)d_in[5];
  const float* fb1 = (const float*)d_in[6];
  const float* fw2 = (const float*)d_in[7];
  const float* fb2 = (const float*)d_in[8];
  float* out = (float*)d_out;
  ushort* ws = (ushort*)d_ws;   // h2g + bf16 weights, 2.53 MB total

  hipLaunchKernelGGL(prep_kernel, dim3(332), dim3(256), 0, stream,
                     fw1, w1, w2, ws);
  hipLaunchKernelGGL(conv_kernel, dim3(2048), dim3(256), 0, stream,
                     x, ws + WS_W1, b1, ws + WS_W2, b2, ws + WS_H2G);
  hipLaunchKernelGGL(fc_kernel, dim3(256), dim3(256), 0, stream,
                     ws + WS_FW1, fb1, fw2, fb2, ws + WS_H2G, out);
}

// Round 17
// 78.656 us; speedup vs baseline: 1.0928x; 1.0928x over previous
//
#include <hip/hip_runtime.h>

typedef float f32x4 __attribute__((ext_vector_type(4)));
typedef short s16x8 __attribute__((ext_vector_type(8)));

#define CB_PLANE 2704   // 52*52 ushorts
#define CB_ROW 52

// d_ws layout (ushort units) — R11 proven
#define WS_H2G  0                 // 4096*288
#define WS_FW1  1179648           // 256*288
#define WS_W1   1253376           // 16*192
#define WS_W2   1256448           // 32*256

// software f32->bf16 RNE (proven R3-R16)
__device__ __forceinline__ ushort f2bf(float f) {
  unsigned u = __float_as_uint(f);
  unsigned r = (u + 0x7fffu + ((u >> 16) & 1u)) >> 16;
  return (ushort)r;
}
__device__ __forceinline__ uint pk2(float a, float b) {
  return (uint)f2bf(a) | ((uint)f2bf(b) << 16);
}

// ---- prep: convert fw1 (73728), w1 (3072), w2 (8192) to bf16. 332*256 exact
__global__ void prep_kernel(const float* __restrict__ fw1,
                            const float* __restrict__ w1,
                            const float* __restrict__ w2,
                            ushort* __restrict__ ws) {
  int i = blockIdx.x * 256 + threadIdx.x;
  if (i < 73728)       ws[WS_FW1 + i] = f2bf(fw1[i]);
  else if (i < 76800)  ws[WS_W1 + i - 73728] = f2bf(w1[i - 73728]);
  else                 ws[WS_W2 + i - 76800] = f2bf(w2[i - 76800]);
}

// ---- conv1 epilogue: bias+relu, scatter into conv2 im2col (proven R8) ----
__device__ __forceinline__ void epi1(ushort* A2, f32x4 acc, int mt, int r16,
                                     int g, float b1v) {
#pragma unroll
  for (int rr = 0; rr < 4; ++rr) {
    int m = mt * 16 + g * 4 + rr;
    int oy = m / 12, ox = m - 12 * oy;
    if (oy < 11 && ox < 11) {
      float v = fmaxf(acc[rr] + b1v, 0.f);
      int py = (oy + 1) >> 2, k2y = (oy + 1) & 3;
      int px = (ox + 1) >> 2, k2x = (ox + 1) & 3;
      A2[(py * 3 + px) * 264 + r16 * 16 + k2y * 4 + k2x] = f2bf(v);
    }
  }
}

// == Kernel A: R14 schedule verbatim; CPB=2, grid 2048, 6 blocks/CU ==
// (cap 85 > observed 64 VGPR need -> no spill; LDS 24672 B x 6 = 148 KB)
__global__ __launch_bounds__(256, 6)
void conv_kernel(const float* __restrict__ x,
                 const ushort* __restrict__ w1b, const float* __restrict__ b1,
                 const ushort* __restrict__ w2b, const float* __restrict__ b2,
                 ushort* __restrict__ h2g)
{
  __shared__ __align__(16) ushort cb[3 * CB_PLANE];   // 16224 B single buffer
  __shared__ __align__(16) ushort A2[16 * 264];       // 8448 B im2col (full 16 rows)

  const int t = threadIdx.x;
  const int w = t >> 6;
  const int r16 = t & 15;
  const int g = (t & 63) >> 4;
  const int cell0 = blockIdx.x * 2;

  // ---- staging descriptors (cell-invariant): 1728 float4 over 7 slots ----
  int goff[7], eoff[7];
#pragma unroll
  for (int i = 0; i < 7; ++i) {
    int q = i * 256 + t;
    int qq = (i < 6 || t < 192) ? q : 0;
    int c = qq / 576; int r2 = qq - c * 576;
    int y = r2 / 12;  int quad = r2 - y * 12;
    goff[i] = c * 36864 + y * 96 + quad;
    eoff[i] = c * CB_PLANE + (y + 2) * CB_ROW + 2 + quad * 4;
  }
  const float4* x4 = (const float4*)x;

  // ---- issue cell0 loads immediately (raw float4) ----
  float4 v[7];
  {
    int n = cell0, b = n >> 6, gg = n & 63;
    int base4 = b * 110592 + (gg >> 3) * 4608 + (gg & 7) * 12;
#pragma unroll
    for (int i = 0; i < 7; ++i)
      if (i < 6 || t < 192) v[i] = x4[base4 + goff[i]];
  }

  // ---- zero cb borders (persist; disjoint from interior writes) + A2 ----
  for (int i = t; i < 600; i += 256) {
    int pl = i / 200, r = i - pl * 200;
    int off;
    if (r < 52)        off = r;
    else if (r < 104)  off = 1300 + (r - 52);
    else if (r < 152)  off = (2 + (r - 104)) * 26;
    else               off = (2 + (r - 152)) * 26 + 25;
    ((uint*)cb)[pl * 1352 + off] = 0u;
  }
  {
    uint4 z = make_uint4(0u, 0u, 0u, 0u);
    uint4* p2 = (uint4*)A2;
    for (int i = t; i < 528; i += 256) p2[i] = z;
  }

  // ---- conv1 B-fragments from pre-converted w1b ----
  s16x8 b1f[6];
#pragma unroll
  for (int s = 0; s < 6; ++s)
    b1f[s] = *(const s16x8*)&w1b[r16 * 192 + s * 32 + g * 8];
  const float b1v = b1[r16];
  const float b2v = b2[(w & 1) * 16 + r16];

  // ---- write cell0 to cb (convert here, once per pixel) ----
#pragma unroll
  for (int i = 0; i < 7; ++i)
    if (i < 6 || t < 192) {
      uint* d = (uint*)&cb[eoff[i]];
      d[0] = pk2(v[i].x, v[i].y);
      d[1] = pk2(v[i].z, v[i].w);
    }

  // conv1 lane constants: wave w owns m-tiles {w, w+4}, wave 2 also 8
  const int mt0 = w, mt1 = w + 4;
  int m0 = mt0 * 16 + r16, m1 = mt1 * 16 + r16, m2_ = 128 + r16;
  const int rA0 = (m0 / 12) * (4 * CB_ROW) + 4 * (m0 % 12);
  const int rA1 = (m1 / 12) * (4 * CB_ROW) + 4 * (m1 % 12);
  const int rA2 = (m2_ / 12) * (4 * CB_ROW) + 4 * (m2_ % 12);

  __syncthreads();

  for (int cl = 0; cl < 2; ++cl) {
    // ---- issue next cell's loads (raw; first USE is after mid-bar) ----
    if (cl < 1) {
      int n = cell0 + 1, b = n >> 6, gg = n & 63;
      int base4 = b * 110592 + (gg >> 3) * 4608 + (gg & 7) * 12;
#pragma unroll
      for (int i = 0; i < 7; ++i)
        if (i < 6 || t < 192) v[i] = x4[base4 + goff[i]];
    }

    // ---- conv1 MFMA on cb (cell cl) ----
    f32x4 a0 = (f32x4){0.f, 0.f, 0.f, 0.f};
    f32x4 a1 = (f32x4){0.f, 0.f, 0.f, 0.f};
    f32x4 a2 = (f32x4){0.f, 0.f, 0.f, 0.f};
#pragma unroll
    for (int s = 0; s < 6; ++s) {
      int sbase = (s >> 1) * CB_PLANE + ((s & 1) * 4 + g) * CB_ROW;
      s16x8 a;
      ((uint2*)&a)[0] = *(const uint2*)&cb[sbase + rA0];
      ((uint2*)&a)[1] = *(const uint2*)&cb[sbase + rA0 + 4];
      a0 = __builtin_amdgcn_mfma_f32_16x16x32_bf16(a, b1f[s], a0, 0, 0, 0);
      ((uint2*)&a)[0] = *(const uint2*)&cb[sbase + rA1];
      ((uint2*)&a)[1] = *(const uint2*)&cb[sbase + rA1 + 4];
      a1 = __builtin_amdgcn_mfma_f32_16x16x32_bf16(a, b1f[s], a1, 0, 0, 0);
      if (w == 2) {
        ((uint2*)&a)[0] = *(const uint2*)&cb[sbase + rA2];
        ((uint2*)&a)[1] = *(const uint2*)&cb[sbase + rA2 + 4];
        a2 = __builtin_amdgcn_mfma_f32_16x16x32_bf16(a, b1f[s], a2, 0, 0, 0);
      }
    }
    epi1(A2, a0, mt0, r16, g, b1v);
    epi1(A2, a1, mt1, r16, g, b1v);
    if (w == 2) epi1(A2, a2, 8, r16, g, b1v);

    __syncthreads();   // conv1 reads of cb done; A2 complete

    // ---- conv2 (waves 0,1) + staging write of cell cl+1 (all waves) ----
    if (w < 2) {
      f32x4 c2acc = (f32x4){0.f, 0.f, 0.f, 0.f};
#pragma unroll
      for (int s2 = 0; s2 < 8; ++s2) {
        uint4 av = *(const uint4*)&A2[r16 * 264 + s2 * 32 + g * 8];
        s16x8 bf = *(const s16x8*)&w2b[(w * 16 + r16) * 256 + s2 * 32 + g * 8];
        c2acc = __builtin_amdgcn_mfma_f32_16x16x32_bf16(*(s16x8*)&av, bf, c2acc, 0, 0, 0);
      }
#pragma unroll
      for (int rr = 0; rr < 4; ++rr) {
        int p2 = g * 4 + rr;
        if (p2 < 9) {
          float vv = fmaxf(c2acc[rr] + b2v, 0.f);
          h2g[(cell0 + cl) * 288 + (w * 16 + r16) * 9 + p2] = f2bf(vv);
        }
      }
    }
    if (cl < 1) {
#pragma unroll
      for (int i = 0; i < 7; ++i)
        if (i < 6 || t < 192) {
          uint* d = (uint*)&cb[eoff[i]];
          d[0] = pk2(v[i].x, v[i].y);
          d[1] = pk2(v[i].z, v[i].w);
        }
    }
    __syncthreads();   // staging writes + conv2 A2 reads complete
  }
}

// ============ Kernel B: fc1(MFMA) + fc2 + softmax (unchanged R11) ==========
__global__ __launch_bounds__(256, 4)
void fc_kernel(const ushort* __restrict__ fw1b, const float* __restrict__ fb1,
               const float* __restrict__ fw2, const float* __restrict__ fb2,
               const ushort* __restrict__ h2g, float* __restrict__ out)
{
  __shared__ __align__(16) ushort h2s[16 * 296];
  __shared__ __align__(16) float h3s[16 * 260];
  __shared__ float ls[16][4];

  const int t = threadIdx.x;
  const int w = t >> 6;
  const int r16 = t & 15;
  const int g = (t & 63) >> 4;
  const int c0 = blockIdx.x * 16;

  const uint* src = (const uint*)(h2g + c0 * 288);
  for (int j = t; j < 2304; j += 256) {
    int r = j / 144, ci = j - r * 144;
    *(uint*)&h2s[r * 296 + 2 * ci] = src[j];
  }
  __syncthreads();

  s16x8 af[9];
#pragma unroll
  for (int s = 0; s < 9; ++s)
    af[s] = *(const s16x8*)&h2s[r16 * 296 + s * 32 + g * 8];

  f32x4 fa0 = (f32x4){0.f,0.f,0.f,0.f}, fa1 = fa0, fa2 = fa0, fa3 = fa0;
#pragma unroll
  for (int s = 0; s < 9; ++s) {
    const int ko = s * 32 + g * 8;
#pragma unroll
    for (int i = 0; i < 4; ++i) {
      s16x8 bf = *(const s16x8*)&fw1b[((w * 4 + i) * 16 + r16) * 288 + ko];
      if (i == 0) fa0 = __builtin_amdgcn_mfma_f32_16x16x32_bf16(af[s], bf, fa0, 0, 0, 0);
      if (i == 1) fa1 = __builtin_amdgcn_mfma_f32_16x16x32_bf16(af[s], bf, fa1, 0, 0, 0);
      if (i == 2) fa2 = __builtin_amdgcn_mfma_f32_16x16x32_bf16(af[s], bf, fa2, 0, 0, 0);
      if (i == 3) fa3 = __builtin_amdgcn_mfma_f32_16x16x32_bf16(af[s], bf, fa3, 0, 0, 0);
    }
  }
#pragma unroll
  for (int i = 0; i < 4; ++i) {
    f32x4 fa = (i == 0) ? fa0 : (i == 1) ? fa1 : (i == 2) ? fa2 : fa3;
    int n = (w * 4 + i) * 16 + r16;
    float fb = fb1[n];
#pragma unroll
    for (int rr = 0; rr < 4; ++rr)
      h3s[(g * 4 + rr) * 260 + n] = fmaxf(fa[rr] + fb, 0.f);
  }
  __syncthreads();

  {
    int u = t >> 2, sub = t & 3;
    int cl = u >> 2, j = u & 3;
    const float4* hp = (const float4*)&h3s[cl * 260];
    const float4* wp = (const float4*)(fw2 + j * 256);
    float p = 0.f;
#pragma unroll
    for (int i = 0; i < 16; ++i) {
      int k4 = sub + 4 * i;
      float4 a = hp[k4], bb = wp[k4];
      p = fmaf(a.x, bb.x, p); p = fmaf(a.y, bb.y, p);
      p = fmaf(a.z, bb.z, p); p = fmaf(a.w, bb.w, p);
    }
    p += __shfl_xor(p, 1);
    p += __shfl_xor(p, 2);
    if (sub == 0) ls[cl][j] = p + fb2[j];
  }
  __syncthreads();

  if (t < 16) {
    float l0 = ls[t][0], l1 = ls[t][1], l2 = ls[t][2], l3 = ls[t][3];
    float m = fmaxf(fmaxf(l0, l1), fmaxf(l2, l3));
    float e0 = __expf(l0 - m), e1 = __expf(l1 - m),
          e2 = __expf(l2 - m), e3 = __expf(l3 - m);
    float inv = 1.f / (e0 + e1 + e2 + e3);
    int n = c0 + t;
    out[n] = e0 * inv;
    out[4096 + n] = e1 * inv;
    out[8192 + n] = e2 * inv;
  }
}

extern "C" void kernel_launch(void* const* d_in, const int* in_sizes, int n_in,
                              void* d_out, int out_size, void* d_ws, size_t ws_size,
                              hipStream_t stream) {
  const float* x   = (const float*)d_in[0];
  const float* w1  = (const float*)d_in[1];
  const float* b1  = (const float*)d_in[2];
  const float* w2  = (const float*)d_in[3];
  const float* b2  = (const float*)d_in[4];
  const float* fw1 = (const float*)d_in[5];
  const float* fb1 = (const float*)d_in[6];
  const float* fw2 = (const float*)d_in[7];
  const float* fb2 = (const float*)d_in[8];
  float* out = (float*)d_out;
  ushort* ws = (ushort*)d_ws;   // h2g + bf16 weights, 2.53 MB total

  hipLaunchKernelGGL(prep_kernel, dim3(332), dim3(256), 0, stream,
                     fw1, w1, w2, ws);
  hipLaunchKernelGGL(conv_kernel, dim3(2048), dim3(256), 0, stream,
                     x, ws + WS_W1, b1, ws + WS_W2, b2, ws + WS_H2G);
  hipLaunchKernelGGL(fc_kernel, dim3(256), dim3(256), 0, stream,
                     ws + WS_FW1, fb1, fw2, fb2, ws + WS_H2G, out);
}

// Round 19
// 61.877 us; speedup vs baseline: 1.3891x; 1.2712x over previous
//
#include <hip/hip_runtime.h>

typedef float f32x4 __attribute__((ext_vector_type(4)));
typedef short s16x8 __attribute__((ext_vector_type(8)));

// d_ws layout (ushort units) — R11 proven
#define WS_H2G  0                 // 4096*288
#define WS_FW1  1179648           // 256*288
#define WS_W1   1253376           // 16*192
#define WS_W2   1256448           // 32*256

// software f32->bf16 RNE (proven R3-R17)
__device__ __forceinline__ ushort f2bf(float f) {
  unsigned u = __float_as_uint(f);
  unsigned r = (u + 0x7fffu + ((u >> 16) & 1u)) >> 16;
  return (ushort)r;
}
__device__ __forceinline__ uint pk2(float a, float b) {
  return (uint)f2bf(a) | ((uint)f2bf(b) << 16);
}

// direct HBM->LDS, 16B/lane, zero VGPR data cost.
// C-style casts: clang allows addrspacecast here (reinterpret_cast does not).
__device__ __forceinline__ void gload16(const void* g, void* l) {
  __builtin_amdgcn_global_load_lds(
      (const __attribute__((address_space(1))) void*)g,
      (__attribute__((address_space(3))) void*)l, 16, 0, 0);
}

// ---- prep: convert fw1 (73728), w1 (3072), w2 (8192) to bf16. 332*256 exact
__global__ void prep_kernel(const float* __restrict__ fw1,
                            const float* __restrict__ w1,
                            const float* __restrict__ w2,
                            ushort* __restrict__ ws) {
  int i = blockIdx.x * 256 + threadIdx.x;
  if (i < 73728)       ws[WS_FW1 + i] = f2bf(fw1[i]);
  else if (i < 76800)  ws[WS_W1 + i - 73728] = f2bf(w1[i - 73728]);
  else                 ws[WS_W2 + i - 76800] = f2bf(w2[i - 76800]);
}

// ---- conv1 A-fragment from UNPADDED fp32 LDS cell: clamp+mask (R8-proven) ----
__device__ __forceinline__ s16x8 fragA(const float* cbf, int f, bool rm,
                                       bool e0, bool e3) {
  const float2* p = (const float2*)(cbf + f);    // f even -> 8B aligned
  float2 q0 = p[e0 ? 1 : 0];                     // addr-clamped, value-masked
  float2 q1 = p[1];
  float2 q2 = p[2];
  float2 q3 = p[e3 ? 2 : 3];
  uint rmu = rm ? 0xFFFFFFFFu : 0u;
  uint m0 = e0 ? 0u : rmu, m3 = e3 ? 0u : rmu;
  s16x8 a;
  ((uint*)&a)[0] = pk2(q0.x, q0.y) & m0;
  ((uint*)&a)[1] = pk2(q1.x, q1.y) & rmu;
  ((uint*)&a)[2] = pk2(q2.x, q2.y) & rmu;
  ((uint*)&a)[3] = pk2(q3.x, q3.y) & m3;
  return a;
}

// ---- conv1 epilogue: bias+relu, scatter into conv2 im2col (rows 0..8) ----
__device__ __forceinline__ void epi1(ushort* A2, f32x4 acc, int mt, int r16,
                                     int g, float b1v) {
#pragma unroll
  for (int rr = 0; rr < 4; ++rr) {
    int m = mt * 16 + g * 4 + rr;
    int oy = m / 12, ox = m - 12 * oy;
    if (oy < 11 && ox < 11) {
      float v = fmaxf(acc[rr] + b1v, 0.f);
      int py = (oy + 1) >> 2, k2y = (oy + 1) & 3;
      int px = (ox + 1) >> 2, k2x = (ox + 1) & 3;
      A2[(py * 3 + px) * 264 + r16 * 16 + k2y * 4 + k2x] = f2bf(v);
    }
  }
}

// == Kernel A: conv1+conv2, 2 cells/block, global_load_lds staging ==
// Single smem array: A2 = first 4752 B (9 live rows; r16>=9 overflow reads land
// in cbf region -> deterministic-irrelevant, feed only discarded C rows);
// cbf = unpadded [3][48][48] fp32 at byte 4752. Total 32400 B -> 5 blocks/CU.
// Staging costs ZERO VGPRs (no v[7] live range -> no spill at min-waves 5).
__global__ __launch_bounds__(256, 5)
void conv_kernel(const float* __restrict__ x,
                 const ushort* __restrict__ w1b, const float* __restrict__ b1,
                 const ushort* __restrict__ w2b, const float* __restrict__ b2,
                 ushort* __restrict__ h2g)
{
  __shared__ __align__(16) uint smem[8100];        // 32400 B
  ushort* A2 = (ushort*)smem;                      // 4752 B
  float* cbf = (float*)((char*)smem + 4752);       // 27648 B, 16-aligned

  const int t = threadIdx.x;
  const int w = t >> 6;
  const int r16 = t & 15;
  const int g = (t & 63) >> 4;
  const int cell0 = blockIdx.x * 2;

  // ---- staging source offsets (cell-invariant): q = i*256+t -> (c,y,quad) ----
  int goff[7];
#pragma unroll
  for (int i = 0; i < 7; ++i) {
    int q = i * 256 + t;
    int qq = (i < 6 || w < 3) ? q : 0;
    int c = qq / 576; int r2 = qq - c * 576;
    int y = r2 / 12;  int quad = r2 - y * 12;
    goff[i] = c * 36864 + y * 96 + quad;
  }
  const float4* x4 = (const float4*)x;

  // ---- issue cell0 staging via global_load_lds (no registers, no borders) ----
  // LDS float index = q*4 = c*2304 + y*48 + 4*quad  == unpadded [c][48][48]
  {
    int n = cell0, b = n >> 6, gg = n & 63;
    int base4 = b * 110592 + (gg >> 3) * 4608 + (gg & 7) * 12;
#pragma unroll
    for (int i = 0; i < 7; ++i)
      if (i < 6 || w < 3)
        gload16((const void*)(x4 + base4 + goff[i]),
                (char*)cbf + (i * 256 + w * 64) * 16);
  }

  // ---- zero A2 (once; epi1 rewrites same live slots every round) ----
  for (int i = t; i < 1188; i += 256) smem[i] = 0u;

  // ---- conv1 B-fragments from pre-converted w1b ----
  s16x8 b1f[6];
#pragma unroll
  for (int s = 0; s < 6; ++s)
    b1f[s] = *(const s16x8*)&w1b[r16 * 192 + s * 32 + g * 8];
  const float b1v = b1[r16];
  const float b2v = b2[(w & 1) * 16 + r16];

  // conv1 lane constants: wave w owns m-tiles {w, w+4}, wave 2 also 8
  const int mt0 = w, mt1 = w + 4;
  int m0 = mt0 * 16 + r16, m1 = mt1 * 16 + r16, m2_ = 128 + r16;
  const int oy0 = m0 / 12, ox0 = m0 - 12 * oy0;
  const int oy1 = m1 / 12, ox1 = m1 - 12 * oy1;
  const int oy2 = m2_ / 12, ox2 = m2_ - 12 * oy2;
  const int fb0 = 192 * oy0 + 4 * ox0 - 2;
  const int fb1_ = 192 * oy1 + 4 * ox1 - 2;
  const int fb2_ = 192 * oy2 + 4 * ox2 - 2;
  const bool e00 = (ox0 == 0), e30 = (ox0 == 11);
  const bool e01 = (ox1 == 0), e31 = (ox1 == 11);
  const bool e02 = (ox2 == 0), e32 = (ox2 == 11);

  __syncthreads();   // vmcnt(0) drain: cbf(cell0) ready; A2 zeros visible

  for (int cl = 0; cl < 2; ++cl) {
    // ---- conv1 MFMA on cbf (cell cl); fragments assembled clamp+mask ----
    f32x4 a0 = (f32x4){0.f, 0.f, 0.f, 0.f};
    f32x4 a1 = (f32x4){0.f, 0.f, 0.f, 0.f};
    f32x4 a2 = (f32x4){0.f, 0.f, 0.f, 0.f};
#pragma unroll
    for (int s = 0; s < 6; ++s) {
      const int dk = (s & 1) * 4 + g - 2;        // iy = 4*oy + dk
      const int pl = (s >> 1) * 2304;
      bool rm0 = (unsigned)(4 * oy0 + dk) < 48u;
      bool rm1 = (unsigned)(4 * oy1 + dk) < 48u;
      int f0 = fb0 + pl + (rm0 ? 48 * dk : 0);
      int f1 = fb1_ + pl + (rm1 ? 48 * dk : 0);
      a0 = __builtin_amdgcn_mfma_f32_16x16x32_bf16(fragA(cbf, f0, rm0, e00, e30), b1f[s], a0, 0, 0, 0);
      a1 = __builtin_amdgcn_mfma_f32_16x16x32_bf16(fragA(cbf, f1, rm1, e01, e31), b1f[s], a1, 0, 0, 0);
      if (w == 2) {
        bool rm2 = (unsigned)(4 * oy2 + dk) < 48u;
        int f2 = fb2_ + pl + (rm2 ? 48 * dk : 0);
        a2 = __builtin_amdgcn_mfma_f32_16x16x32_bf16(fragA(cbf, f2, rm2, e02, e32), b1f[s], a2, 0, 0, 0);
      }
    }
    epi1(A2, a0, mt0, r16, g, b1v);
    epi1(A2, a1, mt1, r16, g, b1v);
    if (w == 2) epi1(A2, a2, 8, r16, g, b1v);

    __syncthreads();   // conv1 reads of cbf done; A2 complete

    // ---- issue next cell's staging (cbf free); overlaps conv2 ----
    if (cl < 1) {
      int n = cell0 + 1, b = n >> 6, gg = n & 63;
      int base4 = b * 110592 + (gg >> 3) * 4608 + (gg & 7) * 12;
#pragma unroll
      for (int i = 0; i < 7; ++i)
        if (i < 6 || w < 3)
          gload16((const void*)(x4 + base4 + goff[i]),
                  (char*)cbf + (i * 256 + w * 64) * 16);
    }

    // ---- conv2 (waves 0,1): M=9(pad16), N=32, K=256 ----
    // r16>=9 A-reads overflow into cbf (possibly mid-staging): values feed
    // ONLY C rows m>=9 which are discarded (MFMA: A row m -> C row m only).
    if (w < 2) {
      f32x4 c2acc = (f32x4){0.f, 0.f, 0.f, 0.f};
#pragma unroll
      for (int s2 = 0; s2 < 8; ++s2) {
        uint4 av = *(const uint4*)&A2[r16 * 264 + s2 * 32 + g * 8];
        s16x8 bf = *(const s16x8*)&w2b[(w * 16 + r16) * 256 + s2 * 32 + g * 8];
        c2acc = __builtin_amdgcn_mfma_f32_16x16x32_bf16(*(s16x8*)&av, bf, c2acc, 0, 0, 0);
      }
#pragma unroll
      for (int rr = 0; rr < 4; ++rr) {
        int p2 = g * 4 + rr;
        if (p2 < 9) {
          float vv = fmaxf(c2acc[rr] + b2v, 0.f);
          h2g[(cell0 + cl) * 288 + (w * 16 + r16) * 9 + p2] = f2bf(vv);
        }
      }
    }
    __syncthreads();   // vmcnt(0) drain: next cell staged; A2 reads complete
  }
}

// ============ Kernel B: fc1(MFMA) + fc2 + softmax (unchanged R11) ==========
__global__ __launch_bounds__(256, 4)
void fc_kernel(const ushort* __restrict__ fw1b, const float* __restrict__ fb1,
               const float* __restrict__ fw2, const float* __restrict__ fb2,
               const ushort* __restrict__ h2g, float* __restrict__ out)
{
  __shared__ __align__(16) ushort h2s[16 * 296];
  __shared__ __align__(16) float h3s[16 * 260];
  __shared__ float ls[16][4];

  const int t = threadIdx.x;
  const int w = t >> 6;
  const int r16 = t & 15;
  const int g = (t & 63) >> 4;
  const int c0 = blockIdx.x * 16;

  const uint* src = (const uint*)(h2g + c0 * 288);
  for (int j = t; j < 2304; j += 256) {
    int r = j / 144, ci = j - r * 144;
    *(uint*)&h2s[r * 296 + 2 * ci] = src[j];
  }
  __syncthreads();

  s16x8 af[9];
#pragma unroll
  for (int s = 0; s < 9; ++s)
    af[s] = *(const s16x8*)&h2s[r16 * 296 + s * 32 + g * 8];

  f32x4 fa0 = (f32x4){0.f,0.f,0.f,0.f}, fa1 = fa0, fa2 = fa0, fa3 = fa0;
#pragma unroll
  for (int s = 0; s < 9; ++s) {
    const int ko = s * 32 + g * 8;
#pragma unroll
    for (int i = 0; i < 4; ++i) {
      s16x8 bf = *(const s16x8*)&fw1b[((w * 4 + i) * 16 + r16) * 288 + ko];
      if (i == 0) fa0 = __builtin_amdgcn_mfma_f32_16x16x32_bf16(af[s], bf, fa0, 0, 0, 0);
      if (i == 1) fa1 = __builtin_amdgcn_mfma_f32_16x16x32_bf16(af[s], bf, fa1, 0, 0, 0);
      if (i == 2) fa2 = __builtin_amdgcn_mfma_f32_16x16x32_bf16(af[s], bf, fa2, 0, 0, 0);
      if (i == 3) fa3 = __builtin_amdgcn_mfma_f32_16x16x32_bf16(af[s], bf, fa3, 0, 0, 0);
    }
  }
#pragma unroll
  for (int i = 0; i < 4; ++i) {
    f32x4 fa = (i == 0) ? fa0 : (i == 1) ? fa1 : (i == 2) ? fa2 : fa3;
    int n = (w * 4 + i) * 16 + r16;
    float fb = fb1[n];
#pragma unroll
    for (int rr = 0; rr < 4; ++rr)
      h3s[(g * 4 + rr) * 260 + n] = fmaxf(fa[rr] + fb, 0.f);
  }
  __syncthreads();

  {
    int u = t >> 2, sub = t & 3;
    int cl = u >> 2, j = u & 3;
    const float4* hp = (const float4*)&h3s[cl * 260];
    const float4* wp = (const float4*)(fw2 + j * 256);
    float p = 0.f;
#pragma unroll
    for (int i = 0; i < 16; ++i) {
      int k4 = sub + 4 * i;
      float4 a = hp[k4], bb = wp[k4];
      p = fmaf(a.x, bb.x, p); p = fmaf(a.y, bb.y, p);
      p = fmaf(a.z, bb.z, p); p = fmaf(a.w, bb.w, p);
    }
    p += __shfl_xor(p, 1);
    p += __shfl_xor(p, 2);
    if (sub == 0) ls[cl][j] = p + fb2[j];
  }
  __syncthreads();

  if (t < 16) {
    float l0 = ls[t][0], l1 = ls[t][1], l2 = ls[t][2], l3 = ls[t][3];
    float m = fmaxf(fmaxf(l0, l1), fmaxf(l2, l3));
    float e0 = __expf(l0 - m), e1 = __expf(l1 - m),
          e2 = __expf(l2 - m), e3 = __expf(l3 - m);
    float inv = 1.f / (e0 + e1 + e2 + e3);
    int n = c0 + t;
    out[n] = e0 * inv;
    out[4096 + n] = e1 * inv;
    out[8192 + n] = e2 * inv;
  }
}

extern "C" void kernel_launch(void* const* d_in, const int* in_sizes, int n_in,
                              void* d_out, int out_size, void* d_ws, size_t ws_size,
                              hipStream_t stream) {
  const float* x   = (const float*)d_in[0];
  const float* w1  = (const float*)d_in[1];
  const float* b1  = (const float*)d_in[2];
  const float* w2  = (const float*)d_in[3];
  const float* b2  = (const float*)d_in[4];
  const float* fw1 = (const float*)d_in[5];
  const float* fb1 = (const float*)d_in[6];
  const float* fw2 = (const float*)d_in[7];
  const float* fb2 = (const float*)d_in[8];
  float* out = (float*)d_out;
  ushort* ws = (ushort*)d_ws;   // h2g + bf16 weights, 2.53 MB total

  hipLaunchKernelGGL(prep_kernel, dim3(332), dim3(256), 0, stream,
                     fw1, w1, w2, ws);
  hipLaunchKernelGGL(conv_kernel, dim3(2048), dim3(256), 0, stream,
                     x, ws + WS_W1, b1, ws + WS_W2, b2, ws + WS_H2G);
  hipLaunchKernelGGL(fc_kernel, dim3(256), dim3(256), 0, stream,
                     ws + WS_FW1, fb1, fw2, fb2, ws + WS_H2G, out);
}